// Round 1
// baseline (903.732 us; speedup 1.0000x reference)
//
#include <hip/hip_runtime.h>
#include <hip/hip_cooperative_groups.h>
#include <math.h>

namespace cg = cooperative_groups;

// Problem constants (match reference)
constexpr int EN = 200000;   // edges == nodes
constexpr int D  = 128;      // embedding dim
constexpr int R  = 4;        // relation types
constexpr float NEG = 0.01f;

constexpr int NBLK = 1024;               // cooperative grid: 4 blocks/CU on 256 CUs
constexpr int NCH  = (EN + 1023) / 1024; // 196 scan chunks

static inline int ceil_div(int a, int b) { return (a + b - 1) / b; }

typedef __attribute__((ext_vector_type(8))) __bf16 bf16x8;
typedef __attribute__((ext_vector_type(4))) float f32x4;

// ---------- bf16 helpers (RNE) ----------
__device__ __forceinline__ unsigned short f2bf(float f) {
    union { float f; unsigned u; } v; v.f = f;
    unsigned u = v.u + 0x7fffu + ((v.u >> 16) & 1u);
    return (unsigned short)(u >> 16);
}
__device__ __forceinline__ unsigned pack2bf(float a, float b) {
    return (unsigned)f2bf(a) | ((unsigned)f2bf(b) << 16);
}
__device__ __forceinline__ float bflo(unsigned m) { return __uint_as_float(m << 16); }
__device__ __forceinline__ float bfhi(unsigned m) { return __uint_as_float(m & 0xffff0000u); }

// ---------- W pre-swizzle to MFMA A-frag bf16 ----------
__device__ __forceinline__ void wswz_one(const float* __restrict__ w,
                                         unsigned short* __restrict__ wsw, int t) {
    int lane = t & 63, mt = (t >> 6) & 7, s = (t >> 9) & 3, r = t >> 11;
    int q = lane >> 4, n = mt * 16 + (lane & 15);
    union { unsigned short us[8]; uint4 u4; } o;
    #pragma unroll
    for (int j = 0; j < 8; ++j) {
        int k = s * 32 + q * 8 + j;
        o.us[j] = f2bf(w[((size_t)r * D + k) * D + n]);
    }
    *(uint4*)(wsw + (size_t)t * 8) = o.u4;
}

// ================= cooperative preprocessing + layer 1 =================
// P0 zero cnt/rcnt/ccur + W prep | P1 histogram | P2 chunk sums |
// P3 (blk0) scan partials + padded relation bases + bk pad-init |
// P4 col_start | P5 bucket | P6 layer-1 (x = ones) -> xb1
__global__ __launch_bounds__(256, 4)
void k_coop(const int* __restrict__ row, const int* __restrict__ col,
            const int* __restrict__ etyp, const float* __restrict__ attr,
            const float* __restrict__ w1, const float* __restrict__ w2,
            const float* __restrict__ w3, const float* __restrict__ b1,
            int* __restrict__ cnt, int* __restrict__ rcnt,
            int* __restrict__ part, int* __restrict__ rbase,
            int* __restrict__ cursor, int* __restrict__ ccur,
            int* __restrict__ col_start,
            int* __restrict__ bk_row, int* __restrict__ bk_dst,
            float* __restrict__ bk_coef,
            float* __restrict__ scoef, unsigned char* __restrict__ styp,
            unsigned short* __restrict__ w2b, unsigned short* __restrict__ w3b,
            float* __restrict__ s1, unsigned* __restrict__ xb1)
{
    cg::grid_group grid = cg::this_grid();
    const int t = threadIdx.x;
    const int bid = blockIdx.x;
    const int gid = bid * 256 + t;

    __shared__ int sm[256];
    __shared__ int lr[R];
    __shared__ int lcnt[R];
    __shared__ int lbase[R];
    __shared__ int sbase[R + 1];
    __shared__ int scnt2[R];
    __shared__ float ls1[R * D];
    __shared__ float lb[D];

    // ---- P0: zero counters + weight prep (independent work folded in) ----
    if (gid < EN + 4) cnt[gid] = 0;          // rcnt is contiguous after cnt
    if (gid < EN) ccur[gid] = 0;
    if (gid < 8192) {
        wswz_one(w2, w2b, gid);
    } else if (gid < 16384) {
        wswz_one(w3, w3b, gid - 8192);
    } else if (gid < 16896) {
        int t2 = gid - 16384;                // 0..511: colsum(W1)
        int r = t2 >> 7, j = t2 & (D - 1);
        float s = 0.f;
        for (int k = 0; k < D; ++k) s += w1[((r << 7) + k) * D + j];
        s1[t2] = s;
    }
    grid.sync();

    // ---- P1: degree histogram + relation counts ----
    if (t < R) lr[t] = 0;
    __syncthreads();
    if (gid < EN) {
        atomicAdd(&cnt[col[gid]], 1);
        atomicAdd(&lr[etyp[gid]], 1);
    }
    __syncthreads();
    if (t < R && lr[t]) atomicAdd(&rcnt[t], lr[t]);
    grid.sync();

    // ---- P2: per-1024-chunk sums ----
    if (bid < NCH) {
        int base = bid * 1024 + t * 4;
        int s = 0;
        #pragma unroll
        for (int i = 0; i < 4; ++i) { int idx = base + i; if (idx < EN) s += cnt[idx]; }
        sm[t] = s; __syncthreads();
        for (int off = 128; off > 0; off >>= 1) {
            if (t < off) sm[t] += sm[t + off];
            __syncthreads();
        }
        if (t == 0) part[bid] = sm[0];
    }
    grid.sync();

    // ---- P3: scan partials + 16-padded relation bases + bk pad-init ----
    if (bid == 0) {
        sm[t] = (t < NCH) ? part[t] : 0;
        __syncthreads();
        for (int off = 1; off < 256; off <<= 1) {
            int u = 0;
            if (t >= off) u = sm[t - off];
            __syncthreads();
            sm[t] += u;
            __syncthreads();
        }
        if (t < NCH) part[t] = (t > 0) ? sm[t - 1] : 0;
        if (t == 0) {
            int s = 0;
            for (int r = 0; r < R; ++r) {
                sbase[r] = s; rbase[r] = s; cursor[r] = s;
                int c = rcnt[r]; scnt2[r] = c;
                s += (c + 15) & ~15;          // 16-aligned bucket regions
            }
            sbase[R] = s; rbase[R] = s;
            col_start[EN] = EN;
        }
        __syncthreads();
        // pads: coef=0 (no contribution), row=0 (safe gather), dst=EN (dump row)
        for (int r = 0; r < R; ++r) {
            int ps = sbase[r] + scnt2[r], pe = sbase[r + 1];
            for (int i = ps + t; i < pe; i += 256) {
                bk_row[i] = 0; bk_dst[i] = EN; bk_coef[i] = 0.f;
            }
        }
    }
    grid.sync();

    // ---- P4: col_start (exclusive positions per column) ----
    if (bid < NCH) {
        int base = bid * 1024 + t * 4;
        int v[4]; int s = 0;
        #pragma unroll
        for (int i = 0; i < 4; ++i) { int idx = base + i; v[i] = (idx < EN) ? cnt[idx] : 0; s += v[i]; }
        sm[t] = s; __syncthreads();
        for (int off = 1; off < 256; off <<= 1) {
            int u = 0;
            if (t >= off) u = sm[t - off];
            __syncthreads();
            sm[t] += u;
            __syncthreads();
        }
        int ex = ((t > 0) ? sm[t - 1] : 0) + part[bid];
        #pragma unroll
        for (int i = 0; i < 4; ++i) {
            int idx = base + i;
            if (idx < EN) { col_start[idx] = ex; ex += v[i]; }
        }
    }
    grid.sync();

    // ---- P5: bucket by relation + col-sorted placement + coef ----
    if (t < R) lcnt[t] = 0;
    __syncthreads();
    {
        int e = gid;
        int r = 0, rank = 0, c = 0, rw = 0;
        float cf = 0.f;
        if (e < EN) {
            r = etyp[e];
            rank = atomicAdd(&lcnt[r], 1);
            c = col[e]; rw = row[e];
            int dr = cnt[rw], dc = cnt[c];
            float a = (dr > 0) ? rsqrtf((float)dr) : 0.f;
            float b = (dc > 0) ? rsqrtf((float)dc) : 0.f;
            cf = attr[e] * a * b;
        }
        __syncthreads();
        if (t < R) lbase[t] = lcnt[t] ? atomicAdd(&cursor[t], lcnt[t]) : 0;
        __syncthreads();
        if (e < EN) {
            int pos = lbase[r] + rank;                       // padded relation bucket
            int sp = col_start[c] + atomicAdd(&ccur[c], 1);  // col-sorted position
            bk_row[pos] = rw;
            bk_dst[pos] = sp;
            bk_coef[pos] = cf;
            scoef[sp] = cf;
            styp[sp] = (unsigned char)r;
        }
    }
    grid.sync();

    // ---- P6: layer 1 (x = ones): z1 = leaky(sum coef*colsum(W1) + b1) ----
    ls1[t] = s1[t];
    ls1[t + 256] = s1[t + 256];
    if (t < D) lb[t] = b1[t];
    __syncthreads();
    {
        int lane = t & 63;
        for (int c = bid * 4 + (t >> 6); c < EN; c += NBLK * 4) {
            int st = col_start[c], pe = col_start[c + 1];
            float a0 = 0.f, a1 = 0.f;
            for (int p = st; p < pe; ++p) {
                float cf = scoef[p];
                int tp = styp[p];
                a0 += cf * ls1[tp * D + lane * 2];
                a1 += cf * ls1[tp * D + lane * 2 + 1];
            }
            a0 += lb[lane * 2]; a1 += lb[lane * 2 + 1];
            a0 = (a0 > 0.f) ? a0 : NEG * a0;
            a1 = (a1 > 0.f) ? a1 : NEG * a1;
            xb1[(size_t)c * 64 + lane] = pack2bf(a0, a1);
        }
    }
}

// ================= MFMA GEMM: flat 1-D tile grid over padded buckets =================
// Relation recovered from rbase[] (16-aligned), so p = tile*16 + n16 directly and
// every lane is valid (pads have coef=0, dst=dump row). No idle relation-slices.
__global__ __launch_bounds__(256)
void k_gemm(const unsigned short* __restrict__ xb, const unsigned short* __restrict__ wsw,
            const int* __restrict__ bk_row, const int* __restrict__ bk_dst,
            const float* __restrict__ bk_coef, const int* __restrict__ rbase,
            unsigned short* __restrict__ msgb) {
    const int t = threadIdx.x;
    const int tile = blockIdx.x * 4 + (t >> 6);
    __shared__ unsigned short xpose[4][16 * 144];   // 18 KB; wave-private regions
    const int e16 = tile * 16;
    if (e16 >= rbase[R]) return;            // wave-uniform early exit (few tail tiles)
    const int r = (e16 >= rbase[1]) + (e16 >= rbase[2]) + (e16 >= rbase[3]);
    const int l = t & 63, q = l >> 4, n16 = l & 15;
    const int p = e16 + n16;                // always in-bounds (padded buckets)
    const int srow = bk_row[p];
    const int dp = bk_dst[p];
    const float cf = bk_coef[p];

    // B-frags: x[edge][k], 16 B per lane per K-step
    const unsigned short* xrow = xb + (size_t)srow * D;
    bf16x8 xf[4];
    #pragma unroll
    for (int s = 0; s < 4; ++s)
        xf[s] = *(const bf16x8*)(xrow + s * 32 + q * 8);

    // A-frags: swizzled W, L1/L2-resident
    const unsigned short* wr = wsw + ((size_t)r * 2048 + l) * 8;

    f32x4 acc[8];
    #pragma unroll
    for (int mt = 0; mt < 8; ++mt) acc[mt] = (f32x4){0.f, 0.f, 0.f, 0.f};

    #pragma unroll
    for (int s = 0; s < 4; ++s) {
        #pragma unroll
        for (int mt = 0; mt < 8; ++mt) {
            bf16x8 wf = *(const bf16x8*)(wr + (size_t)(s * 512 + mt * 64) * 8);
            acc[mt] = __builtin_amdgcn_mfma_f32_16x16x32_bf16(wf, xf[s], acc[mt], 0, 0, 0);
        }
    }

    // epilogue: scale, pack, transpose through wave-private LDS, coalesced store
    unsigned short* lbuf = xpose[t >> 6];
    #pragma unroll
    for (int mt = 0; mt < 8; ++mt) {
        uint2 u;
        u.x = pack2bf(acc[mt].x * cf, acc[mt].y * cf);
        u.y = pack2bf(acc[mt].z * cf, acc[mt].w * cf);
        *(uint2*)&lbuf[n16 * 144 + mt * 16 + q * 4] = u;
    }
    #pragma unroll
    for (int ro = 0; ro < 4; ++ro) {
        int e = ro * 4 + q;
        uint4 v = *(const uint4*)&lbuf[e * 144 + n16 * 8];
        int rdp = __shfl(dp, e);
        *(uint4*)(msgb + (size_t)rdp * D + n16 * 8) = v;
    }
}

// ================= sequential gather + bias + leaky + combine =================
// mode 2: z2out = leaky(gather(msg) + b2)                       (bf16)
// mode 3: dout = (1 + z1 + z2 + leaky(gather(msg) + b3)) * 0.25 (fp32)
__global__ void k_agg(const unsigned* __restrict__ msgb32, const float* __restrict__ bias,
                      const int* __restrict__ col_start,
                      unsigned* __restrict__ z2out,
                      const unsigned* __restrict__ z1in, const unsigned* __restrict__ z2in,
                      float* __restrict__ dout, int mode) {
    __shared__ float lb[D];
    int t = threadIdx.x;
    if (t < D) lb[t] = bias[t];
    __syncthreads();
    int lane = t & 63;
    for (int c = blockIdx.x * 4 + (t >> 6); c < EN; c += gridDim.x * 4) {
        int st = col_start[c], pe = col_start[c + 1];
        float a0 = 0.f, a1 = 0.f;
        for (int p = st; p < pe; ++p) {
            unsigned m = msgb32[(size_t)p * 64 + lane];
            a0 += bflo(m); a1 += bfhi(m);
        }
        a0 += lb[lane * 2]; a1 += lb[lane * 2 + 1];
        a0 = (a0 > 0.f) ? a0 : NEG * a0;
        a1 = (a1 > 0.f) ? a1 : NEG * a1;
        size_t ix = (size_t)c * 64 + lane;
        if (mode == 2) {
            z2out[ix] = pack2bf(a0, a1);
        } else {
            unsigned u1 = z1in[ix], u2 = z2in[ix];
            float2 o;
            o.x = (1.f + bflo(u1) + bflo(u2) + a0) * 0.25f;
            o.y = (1.f + bfhi(u1) + bfhi(u2) + a1) * 0.25f;
            ((float2*)(dout + (size_t)c * D))[lane] = o;
        }
    }
}

extern "C" void kernel_launch(void* const* d_in, const int* in_sizes, int n_in,
                              void* d_out, int out_size, void* d_ws, size_t ws_size,
                              hipStream_t stream) {
    const int*   eidx = (const int*)d_in[0];     // [2, E]
    const int*   row  = eidx;
    const int*   col  = eidx + EN;
    const int*   etyp = (const int*)d_in[1];
    const float* attr = (const float*)d_in[2];
    const float* w1   = (const float*)d_in[3];
    const float* b1   = (const float*)d_in[4];
    const float* w2   = (const float*)d_in[5];
    const float* b2   = (const float*)d_in[6];
    const float* w3   = (const float*)d_in[7];
    const float* b3   = (const float*)d_in[8];
    float* dout = (float*)d_out;

    // workspace layout (~160 MB; ws is ~409.6 MB per harness poison size)
    char* wsb = (char*)d_ws;
    size_t off = 0;
    unsigned short* msgb = (unsigned short*)(wsb + off); off += (size_t)(EN + 1) * D * 2 + 512;
    unsigned short* xb1  = (unsigned short*)(wsb + off); off += (size_t)EN * D * 2;  // z1
    unsigned short* xb2  = (unsigned short*)(wsb + off); off += (size_t)EN * D * 2;  // z2
    int*   col_start = (int*)(wsb + off); off += 800032;
    int*   cnt       = (int*)(wsb + off); off += (size_t)EN * 4;
    int*   rcnt      = (int*)(wsb + off); off += 16;      // contiguous after cnt!
    float* scoef     = (float*)(wsb + off); off += (size_t)EN * 4;
    unsigned char* styp = (unsigned char*)(wsb + off); off += 200064;
    int*   bk_row    = (int*)(wsb + off); off += (size_t)(EN + 64) * 4;
    int*   bk_dst    = (int*)(wsb + off); off += (size_t)(EN + 64) * 4;
    float* bk_coef   = (float*)(wsb + off); off += (size_t)(EN + 64) * 4;
    unsigned short* w2b = (unsigned short*)(wsb + off); off += 131072;
    unsigned short* w3b = (unsigned short*)(wsb + off); off += 131072;
    int*   part      = (int*)(wsb + off); off += 1024;
    int*   rbase     = (int*)(wsb + off); off += 32;
    int*   cursor    = (int*)(wsb + off); off += 16;
    float* s1        = (float*)(wsb + off); off += (size_t)R * D * 4;
    int*   ccur      = (int*)msgb;   // aliased: msgb not live until GEMM layer 2

    dim3 blk(256);

    // cooperative: zero + histogram + scans + bucket + W-prep + layer 1 (1 dispatch)
    unsigned* xb1u = (unsigned*)xb1;
    void* cargs[] = {
        (void*)&row, (void*)&col, (void*)&etyp, (void*)&attr,
        (void*)&w1, (void*)&w2, (void*)&w3, (void*)&b1,
        (void*)&cnt, (void*)&rcnt, (void*)&part, (void*)&rbase,
        (void*)&cursor, (void*)&ccur, (void*)&col_start,
        (void*)&bk_row, (void*)&bk_dst, (void*)&bk_coef,
        (void*)&scoef, (void*)&styp, (void*)&w2b, (void*)&w3b,
        (void*)&s1, (void*)&xb1u
    };
    hipLaunchCooperativeKernel((void*)k_coop, dim3(NBLK), blk, cargs, 0, stream);

    // layers 2,3: flat-tile GEMM + grid-stride aggregate
    const int nTiles = ceil_div(EN + 64, 16);        // >= total padded tiles
    const int gB = ceil_div(nTiles, 4);              // 3126 blocks
    k_gemm<<<gB, blk, 0, stream>>>(xb1, w2b, bk_row, bk_dst, bk_coef, rbase, msgb);
    k_agg<<<2048, blk, 0, stream>>>((const unsigned*)msgb, b2, col_start,
                                    (unsigned*)xb2, nullptr, nullptr, nullptr, 2);
    k_gemm<<<gB, blk, 0, stream>>>(xb2, w3b, bk_row, bk_dst, bk_coef, rbase, msgb);
    k_agg<<<2048, blk, 0, stream>>>((const unsigned*)msgb, b3, col_start,
                                    nullptr, (const unsigned*)xb1, (const unsigned*)xb2,
                                    dout, 3);
}

// Round 2
// 320.902 us; speedup vs baseline: 2.8162x; 2.8162x over previous
//
#include <hip/hip_runtime.h>
#include <math.h>

// Problem constants (match reference)
constexpr int EN = 200000;   // edges == nodes
constexpr int D  = 128;      // embedding dim
constexpr int R  = 4;        // relation types
constexpr float NEG = 0.01f;

constexpr int NBLKE = (EN + 255) / 256;   // 782 histogram blocks
constexpr int NPREP = 66;                 // 16896 prep threads
constexpr int NCH   = (EN + 1023) / 1024; // 196 scan chunks

static inline int ceil_div(int a, int b) { return (a + b - 1) / b; }

typedef __attribute__((ext_vector_type(8))) __bf16 bf16x8;
typedef __attribute__((ext_vector_type(4))) float f32x4;

// ---------- bf16 helpers (RNE) ----------
__device__ __forceinline__ unsigned short f2bf(float f) {
    union { float f; unsigned u; } v; v.f = f;
    unsigned u = v.u + 0x7fffu + ((v.u >> 16) & 1u);
    return (unsigned short)(u >> 16);
}
__device__ __forceinline__ unsigned pack2bf(float a, float b) {
    return (unsigned)f2bf(a) | ((unsigned)f2bf(b) << 16);
}
__device__ __forceinline__ float bflo(unsigned m) { return __uint_as_float(m << 16); }
__device__ __forceinline__ float bfhi(unsigned m) { return __uint_as_float(m & 0xffff0000u); }

// ---------- W pre-swizzle to MFMA A-frag bf16 ----------
__device__ __forceinline__ void wswz_one(const float* __restrict__ w,
                                         unsigned short* __restrict__ wsw, int t) {
    int lane = t & 63, mt = (t >> 6) & 7, s = (t >> 9) & 3, r = t >> 11;
    int q = lane >> 4, n = mt * 16 + (lane & 15);
    union { unsigned short us[8]; uint4 u4; } o;
    #pragma unroll
    for (int j = 0; j < 8; ++j) {
        int k = s * 32 + q * 8 + j;
        o.us[j] = f2bf(w[((size_t)r * D + k) * D + n]);
    }
    *(uint4*)(wsw + (size_t)t * 8) = o.u4;
}

// ---------- histogram (col degree + relation counts) + W prep, one dispatch ----------
// blocks [0, NBLKE): histogram; blocks [NBLKE, NBLKE+NPREP): swizzle W2,W3 + colsum(W1)
__global__ void k_cntprep(const int* __restrict__ col, const int* __restrict__ etyp,
                          const float* __restrict__ w1, const float* __restrict__ w2,
                          const float* __restrict__ w3,
                          int* __restrict__ cnt, int* __restrict__ rcnt,
                          unsigned short* __restrict__ w2b, unsigned short* __restrict__ w3b,
                          float* __restrict__ s1) {
    const int b = blockIdx.x, t = threadIdx.x;
    if (b < NBLKE) {
        __shared__ int lr[R];
        if (t < R) lr[t] = 0;
        __syncthreads();
        int e = b * 256 + t;
        if (e < EN) {
            atomicAdd(&cnt[col[e]], 1);
            atomicAdd(&lr[etyp[e]], 1);
        }
        __syncthreads();
        if (t < R && lr[t]) atomicAdd(&rcnt[t], lr[t]);
    } else {
        int g = (b - NBLKE) * 256 + t;     // 0..16895
        if (g < 8192) {
            wswz_one(w2, w2b, g);
        } else if (g < 16384) {
            wswz_one(w3, w3b, g - 8192);
        } else if (g < 16896) {
            int t2 = g - 16384;            // 0..511: colsum(W1)
            int r = t2 >> 7, j = t2 & (D - 1);
            float s = 0.f;
            for (int k = 0; k < D; ++k) s += w1[((r << 7) + k) * D + j];
            s1[t2] = s;
        }
    }
}

// ---------- scan stage 1: per-1024-chunk sums ----------
__global__ void k_scan1(const int* __restrict__ cnt, int* __restrict__ part, int n) {
    __shared__ int sm[256];
    int t = threadIdx.x;
    int base = blockIdx.x * 1024 + t * 4;
    int s = 0;
    #pragma unroll
    for (int i = 0; i < 4; ++i) { int idx = base + i; if (idx < n) s += cnt[idx]; }
    sm[t] = s; __syncthreads();
    for (int off = 128; off > 0; off >>= 1) {
        if (t < off) sm[t] += sm[t + off];
        __syncthreads();
    }
    if (t == 0) part[blockIdx.x] = sm[0];
}

// ---------- scan stage 2: partials scan + 16-padded relation bases + bk pad-init ----------
__global__ void k_scan2(int* __restrict__ part, int nb,
                        const int* __restrict__ rcnt, int* __restrict__ rbase,
                        int* __restrict__ cursor, int* __restrict__ col_start,
                        int* __restrict__ bk_row, int* __restrict__ bk_dst,
                        float* __restrict__ bk_coef) {
    __shared__ int sm[256];
    __shared__ int sbase[R + 1];
    __shared__ int scnt[R];
    int t = threadIdx.x;
    sm[t] = (t < nb) ? part[t] : 0;
    __syncthreads();
    for (int off = 1; off < 256; off <<= 1) {
        int u = 0;
        if (t >= off) u = sm[t - off];
        __syncthreads();
        sm[t] += u;
        __syncthreads();
    }
    int ex = (t > 0) ? sm[t - 1] : 0;
    if (t < nb) part[t] = ex;
    if (t == 0) {
        int s = 0;
        for (int r = 0; r < R; ++r) {
            sbase[r] = s; rbase[r] = s; cursor[r] = s;
            int c = rcnt[r]; scnt[r] = c;
            s += (c + 15) & ~15;              // 16-aligned bucket regions
        }
        sbase[R] = s; rbase[R] = s;
        col_start[EN] = EN;
    }
    __syncthreads();
    // pads: coef=0 (no contribution), row=0 (safe gather), dst=EN (dump row)
    for (int r = 0; r < R; ++r) {
        int ps = sbase[r] + scnt[r], pe = sbase[r + 1];
        for (int i = ps + t; i < pe; i += 256) {
            bk_row[i] = 0; bk_dst[i] = EN; bk_coef[i] = 0.f;
        }
    }
}

// ---------- scan stage 3: col_start (+ ccur zeroing) ----------
__global__ void k_scan3(const int* __restrict__ cnt, const int* __restrict__ part,
                        int* __restrict__ col_start, int* __restrict__ ccur, int n) {
    __shared__ int sm[256];
    int t = threadIdx.x;
    int base = blockIdx.x * 1024 + t * 4;
    int v[4]; int s = 0;
    #pragma unroll
    for (int i = 0; i < 4; ++i) { int idx = base + i; v[i] = (idx < n) ? cnt[idx] : 0; s += v[i]; }
    sm[t] = s; __syncthreads();
    for (int off = 1; off < 256; off <<= 1) {
        int u = 0;
        if (t >= off) u = sm[t - off];
        __syncthreads();
        sm[t] += u;
        __syncthreads();
    }
    int ex = ((t > 0) ? sm[t - 1] : 0) + part[blockIdx.x];
    #pragma unroll
    for (int i = 0; i < 4; ++i) {
        int idx = base + i;
        if (idx < n) { col_start[idx] = ex; ex += v[i]; ccur[idx] = 0; }
    }
}

// ---------- bucket by relation (16-padded) + col-sorted placement + coef ----------
__global__ void k_bucket(const int* __restrict__ row, const int* __restrict__ col,
                         const int* __restrict__ etype, const float* __restrict__ attr,
                         const int* __restrict__ cnt, const int* __restrict__ col_start,
                         int* __restrict__ cursor, int* __restrict__ ccur,
                         int* __restrict__ bk_row, int* __restrict__ bk_dst,
                         float* __restrict__ bk_coef,
                         float* __restrict__ scoef, unsigned char* __restrict__ styp,
                         int n) {
    __shared__ int lcnt[R];
    __shared__ int lbase[R];
    int t = threadIdx.x;
    if (t < R) lcnt[t] = 0;
    __syncthreads();
    int e = blockIdx.x * 256 + t;
    int r = 0, rank = 0, c = 0, rw = 0;
    float cf = 0.f;
    if (e < n) {
        r = etype[e];
        rank = atomicAdd(&lcnt[r], 1);
        c = col[e]; rw = row[e];
        int dr = cnt[rw], dc = cnt[c];
        float a = (dr > 0) ? rsqrtf((float)dr) : 0.f;
        float b = (dc > 0) ? rsqrtf((float)dc) : 0.f;
        cf = attr[e] * a * b;
    }
    __syncthreads();
    if (t < R) lbase[t] = lcnt[t] ? atomicAdd(&cursor[t], lcnt[t]) : 0;
    __syncthreads();
    if (e < n) {
        int pos = lbase[r] + rank;                       // padded relation bucket
        int sp = col_start[c] + atomicAdd(&ccur[c], 1);  // col-sorted position
        bk_row[pos] = rw;
        bk_dst[pos] = sp;
        bk_coef[pos] = cf;
        scoef[sp] = cf;
        styp[sp] = (unsigned char)r;
    }
}

// ---------- layer 1 gather (x = ones): xb1 = bf16(z1) ----------
__global__ void k_phase1(const float* __restrict__ s1, const float* __restrict__ b1,
                         const int* __restrict__ col_start,
                         const unsigned char* __restrict__ styp,
                         const float* __restrict__ scoef,
                         unsigned* __restrict__ xb32) {
    __shared__ float ls1[R * D];
    __shared__ float lb[D];
    int t = threadIdx.x;
    ls1[t] = s1[t];
    ls1[t + 256] = s1[t + 256];
    if (t < D) lb[t] = b1[t];
    __syncthreads();
    int lane = t & 63;
    int c = blockIdx.x * 4 + (t >> 6);
    if (c >= EN) return;
    int st = col_start[c], en = col_start[c + 1];
    float a0 = 0.f, a1 = 0.f;
    for (int p = st; p < en; ++p) {
        float cf = scoef[p];
        int tp = styp[p];
        a0 += cf * ls1[tp * D + lane * 2];
        a1 += cf * ls1[tp * D + lane * 2 + 1];
    }
    a0 += lb[lane * 2]; a1 += lb[lane * 2 + 1];
    a0 = (a0 > 0.f) ? a0 : NEG * a0;
    a1 = (a1 > 0.f) ? a1 : NEG * a1;
    xb32[(size_t)c * 64 + lane] = pack2bf(a0, a1);
}

// ================= MFMA GEMM: flat 1-D tile grid over padded buckets =================
// Relation recovered from rbase[] (16-aligned) -> every lane valid (pads: coef=0,
// dst=dump row). No idle relation-slices, no per-lane validity logic.
__global__ __launch_bounds__(256)
void k_gemm(const unsigned short* __restrict__ xb, const unsigned short* __restrict__ wsw,
            const int* __restrict__ bk_row, const int* __restrict__ bk_dst,
            const float* __restrict__ bk_coef, const int* __restrict__ rbase,
            unsigned short* __restrict__ msgb) {
    const int t = threadIdx.x;
    const int tile = blockIdx.x * 4 + (t >> 6);
    __shared__ unsigned short xpose[4][16 * 144];   // 18 KB; wave-private regions
    const int e16 = tile * 16;
    if (e16 >= rbase[R]) return;            // wave-uniform early exit (tail tiles only)
    const int r = (e16 >= rbase[1]) + (e16 >= rbase[2]) + (e16 >= rbase[3]);
    const int l = t & 63, q = l >> 4, n16 = l & 15;
    const int p = e16 + n16;                // always in-bounds (padded buckets)
    const int srow = bk_row[p];
    const int dp = bk_dst[p];
    const float cf = bk_coef[p];

    // B-frags: x[edge][k], 16 B per lane per K-step
    const unsigned short* xrow = xb + (size_t)srow * D;
    bf16x8 xf[4];
    #pragma unroll
    for (int s = 0; s < 4; ++s)
        xf[s] = *(const bf16x8*)(xrow + s * 32 + q * 8);

    // A-frags: swizzled W, L1/L2-resident
    const unsigned short* wr = wsw + ((size_t)r * 2048 + l) * 8;

    f32x4 acc[8];
    #pragma unroll
    for (int mt = 0; mt < 8; ++mt) acc[mt] = (f32x4){0.f, 0.f, 0.f, 0.f};

    #pragma unroll
    for (int s = 0; s < 4; ++s) {
        #pragma unroll
        for (int mt = 0; mt < 8; ++mt) {
            bf16x8 wf = *(const bf16x8*)(wr + (size_t)(s * 512 + mt * 64) * 8);
            acc[mt] = __builtin_amdgcn_mfma_f32_16x16x32_bf16(wf, xf[s], acc[mt], 0, 0, 0);
        }
    }

    // epilogue: scale, pack, transpose through wave-private LDS, coalesced store
    unsigned short* lbuf = xpose[t >> 6];
    #pragma unroll
    for (int mt = 0; mt < 8; ++mt) {
        uint2 u;
        u.x = pack2bf(acc[mt].x * cf, acc[mt].y * cf);
        u.y = pack2bf(acc[mt].z * cf, acc[mt].w * cf);
        *(uint2*)&lbuf[n16 * 144 + mt * 16 + q * 4] = u;
    }
    #pragma unroll
    for (int ro = 0; ro < 4; ++ro) {
        int e = ro * 4 + q;
        uint4 v = *(const uint4*)&lbuf[e * 144 + n16 * 8];
        int rdp = __shfl(dp, e);
        *(uint4*)(msgb + (size_t)rdp * D + n16 * 8) = v;
    }
}

// ================= sequential gather + bias + leaky + combine =================
// mode 2: z2out = leaky(gather(msg) + b2)                       (bf16)
// mode 3: dout = (1 + z1 + z2 + leaky(gather(msg) + b3)) * 0.25 (fp32)
__global__ void k_agg(const unsigned* __restrict__ msgb32, const float* __restrict__ bias,
                      const int* __restrict__ col_start,
                      unsigned* __restrict__ z2out,
                      const unsigned* __restrict__ z1in, const unsigned* __restrict__ z2in,
                      float* __restrict__ dout, int mode) {
    __shared__ float lb[D];
    int t = threadIdx.x;
    if (t < D) lb[t] = bias[t];
    __syncthreads();
    int lane = t & 63;
    for (int c = blockIdx.x * 4 + (t >> 6); c < EN; c += gridDim.x * 4) {
        int st = col_start[c], pe = col_start[c + 1];
        float a0 = 0.f, a1 = 0.f;
        for (int p = st; p < pe; ++p) {
            unsigned m = msgb32[(size_t)p * 64 + lane];
            a0 += bflo(m); a1 += bfhi(m);
        }
        a0 += lb[lane * 2]; a1 += lb[lane * 2 + 1];
        a0 = (a0 > 0.f) ? a0 : NEG * a0;
        a1 = (a1 > 0.f) ? a1 : NEG * a1;
        size_t ix = (size_t)c * 64 + lane;
        if (mode == 2) {
            z2out[ix] = pack2bf(a0, a1);
        } else {
            unsigned u1 = z1in[ix], u2 = z2in[ix];
            float2 o;
            o.x = (1.f + bflo(u1) + bflo(u2) + a0) * 0.25f;
            o.y = (1.f + bfhi(u1) + bfhi(u2) + a1) * 0.25f;
            ((float2*)(dout + (size_t)c * D))[lane] = o;
        }
    }
}

extern "C" void kernel_launch(void* const* d_in, const int* in_sizes, int n_in,
                              void* d_out, int out_size, void* d_ws, size_t ws_size,
                              hipStream_t stream) {
    const int*   eidx = (const int*)d_in[0];     // [2, E]
    const int*   row  = eidx;
    const int*   col  = eidx + EN;
    const int*   etyp = (const int*)d_in[1];
    const float* attr = (const float*)d_in[2];
    const float* w1   = (const float*)d_in[3];
    const float* b1   = (const float*)d_in[4];
    const float* w2   = (const float*)d_in[5];
    const float* b2   = (const float*)d_in[6];
    const float* w3   = (const float*)d_in[7];
    const float* b3   = (const float*)d_in[8];
    float* dout = (float*)d_out;

    // workspace layout (~160 MB; ws is ~409.6 MB per harness poison size)
    char* wsb = (char*)d_ws;
    size_t off = 0;
    unsigned short* msgb = (unsigned short*)(wsb + off); off += (size_t)(EN + 1) * D * 2 + 512;
    unsigned short* xb1  = (unsigned short*)(wsb + off); off += (size_t)EN * D * 2;  // z1
    unsigned short* xb2  = (unsigned short*)(wsb + off); off += (size_t)EN * D * 2;  // z2
    int*   col_start = (int*)(wsb + off); off += 800032;
    int*   cnt       = (int*)(wsb + off); off += (size_t)EN * 4;
    int*   rcnt      = (int*)(wsb + off); off += 16;      // contiguous after cnt!
    float* scoef     = (float*)(wsb + off); off += (size_t)EN * 4;
    unsigned char* styp = (unsigned char*)(wsb + off); off += 200064;
    int*   bk_row    = (int*)(wsb + off); off += (size_t)(EN + 64) * 4;
    int*   bk_dst    = (int*)(wsb + off); off += (size_t)(EN + 64) * 4;
    float* bk_coef   = (float*)(wsb + off); off += (size_t)(EN + 64) * 4;
    unsigned short* w2b = (unsigned short*)(wsb + off); off += 131072;
    unsigned short* w3b = (unsigned short*)(wsb + off); off += 131072;
    int*   part      = (int*)(wsb + off); off += 1024;
    int*   rbase     = (int*)(wsb + off); off += 32;
    int*   cursor    = (int*)(wsb + off); off += 16;
    float* s1        = (float*)(wsb + off); off += (size_t)R * D * 4;
    int*   ccur      = (int*)msgb;   // aliased: msgb not live until GEMM layer 2

    dim3 blk(256);

    // histogram + W prep (one memset covers cnt + rcnt, contiguous)
    hipMemsetAsync(cnt, 0, (size_t)(EN + 4) * 4, stream);
    k_cntprep<<<NBLKE + NPREP, blk, 0, stream>>>(col, etyp, w1, w2, w3,
                                                 cnt, rcnt, w2b, w3b, s1);

    // scans: cnt -> col_start; scan2 also does padded relation bases + bk pad-init,
    // scan3 also zeroes ccur
    k_scan1<<<NCH, blk, 0, stream>>>(cnt, part, EN);
    k_scan2<<<1, blk, 0, stream>>>(part, NCH, rcnt, rbase, cursor, col_start,
                                   bk_row, bk_dst, bk_coef);
    k_scan3<<<NCH, blk, 0, stream>>>(cnt, part, col_start, ccur, EN);

    // bucket + col-sort placement (+ coef)
    k_bucket<<<NBLKE, blk, 0, stream>>>(row, col, etyp, attr, cnt, col_start,
                                        cursor, ccur, bk_row, bk_dst, bk_coef,
                                        scoef, styp, EN);

    // layer 1 (x = ones)
    k_phase1<<<ceil_div(EN, 4), blk, 0, stream>>>(s1, b1, col_start, styp, scoef,
                                                  (unsigned*)xb1);

    // layers 2,3: flat-tile GEMM + grid-stride aggregate
    const int nTiles = ceil_div(EN + 64, 16);
    const int gB = ceil_div(nTiles, 4);              // 3126 blocks
    k_gemm<<<gB, blk, 0, stream>>>(xb1, w2b, bk_row, bk_dst, bk_coef, rbase, msgb);
    k_agg<<<2048, blk, 0, stream>>>((const unsigned*)msgb, b2, col_start,
                                    (unsigned*)xb2, nullptr, nullptr, nullptr, 2);
    k_gemm<<<gB, blk, 0, stream>>>(xb2, w3b, bk_row, bk_dst, bk_coef, rbase, msgb);
    k_agg<<<2048, blk, 0, stream>>>((const unsigned*)msgb, b3, col_start,
                                    nullptr, (const unsigned*)xb1, (const unsigned*)xb2,
                                    dout, 3);
}